// Round 11
// baseline (76.252 us; speedup 1.0000x reference)
//
#include <hip/hip_runtime.h>
#include <math.h>

#define BN 16
#define DN 2048
#define ADA 1024
#define INTER 1024
#define NW2 32768   // D*RANK*2
#define HALFN 16384
#define KSL 16      // k2 k-slices

typedef __attribute__((address_space(1))) const void gv_t;
typedef __attribute__((address_space(3))) void lv_t;
__device__ __forceinline__ void gload_lds16(const float* g, float* l) {
    __builtin_amdgcn_global_load_lds((gv_t*)g, (lv_t*)l, 16, 0, 0);
}
#define WAITV8() asm volatile("s_waitcnt vmcnt(8)" ::: "memory")
#define WAITV4() asm volatile("s_waitcnt vmcnt(4)" ::: "memory")
#define WAITV0() asm volatile("s_waitcnt vmcnt(0)" ::: "memory")

// ===========================================================================
// K1a: h_pre[m][j] += sum over k-chunk of ada[m][k]*w1[k][j]   (atomic k-split;
// 0.5M atomics total — measured tolerable since r1)
__global__ void k1a(const float* __restrict__ ada, const float* __restrict__ w1,
                    float* __restrict__ h_pre) {
    const int j  = blockIdx.x * 256 + threadIdx.x;
    const int k0 = blockIdx.y * 32;
    __shared__ float a_lds[BN][32];
    for (int idx = threadIdx.x; idx < BN * 32; idx += 256) {
        int m = idx >> 5, kk = idx & 31;
        a_lds[m][kk] = ada[m * ADA + k0 + kk];
    }
    __syncthreads();
    float acc[BN];
#pragma unroll
    for (int m = 0; m < BN; ++m) acc[m] = 0.f;
    for (int kk = 0; kk < 32; ++kk) {
        float w = w1[(k0 + kk) * INTER + j];
#pragma unroll
        for (int m = 0; m < BN; ++m) acc[m] += a_lds[m][kk] * w;
    }
#pragma unroll
    for (int m = 0; m < BN; ++m) atomicAdd(&h_pre[m * INTER + j], acc[m]);
}

// ===========================================================================
// K1b-T: h_t[k][m] = gelu_exact(h_pre[m][k] + b1[k])   (transposed output)
__global__ void k1bt(const float* __restrict__ h_pre, const float* __restrict__ b1,
                     float* __restrict__ h_t) {
    int i = blockIdx.x * 256 + threadIdx.x;     // 16384 elements
    int m = i >> 10, j = i & (INTER - 1);
    float v = h_pre[i] + b1[j];
    float g = 0.5f * v * (1.f + erff(v * 0.70710678118654752f));
    h_t[j * BN + m] = g;
}

// ===========================================================================
// K2w: p2[ks][m][n] = sum_{k in 64-chunk} h_t[k][m] * w2[k][n]
// grid (32 n-tiles, 16 k-slices) = 512 blocks, 256 thr (4 waves), 68 KB LDS
// -> exactly 2 blocks/CU, all co-resident.
// NO BARRIERS in the main loop: each wave owns a private 1 KB n-window and
// 4 private LDS buffers; ordering is per-wave s_waitcnt vmcnt(8) only
// (vmcnt is per-wave; buffers wave-private -> no cross-wave visibility
// needed). Steady state: 12 loads/wave in flight = 96 KB/CU. The shared
// read-only h tile gets one prologue barrier.
__global__ __launch_bounds__(256) void k2w(const float* __restrict__ h_t,
                                           const float* __restrict__ w2,
                                           float* __restrict__ p2) {
    const int tid = threadIdx.x;
    const int wv  = tid >> 6, ln = tid & 63;
    const int n0  = blockIdx.x * 1024;          // block n window (floats)
    const int k0  = blockIdx.y * 64;            // block k range
    __shared__ __align__(16) float wl[4][4][1024];   // [wave][buf][1KB] = 64 KB
    __shared__ __align__(16) float hl[64][16];       // 4 KB shared h tile

    // prologue: stage h (1024 floats), one barrier, then never again
    ((float4*)hl)[tid] = ((const float4*)(h_t + k0 * BN))[tid];
    __syncthreads();

    float4 acc[BN];
#pragma unroll
    for (int m = 0; m < BN; ++m) acc[m] = make_float4(0.f, 0.f, 0.f, 0.f);

    // STAGE(b, ph): 4 k-rows x 1 KB into wave-private buffer b.
    // LDS dst uniform per wave (+ lane*16 hw); src = lane's float4 of the row.
#define STAGE(b, ph) do {                                                     \
    const float* gs_ = w2 + (size_t)(k0 + (ph) * 4) * NW2 + n0                \
                     + wv * 256 + ln * 4;                                     \
    float* ls_ = &wl[wv][b][0];                                               \
    gload_lds16(gs_ + (size_t)0 * NW2, ls_ + 0);                              \
    gload_lds16(gs_ + (size_t)1 * NW2, ls_ + 256);                            \
    gload_lds16(gs_ + (size_t)2 * NW2, ls_ + 512);                            \
    gload_lds16(gs_ + (size_t)3 * NW2, ls_ + 768);                            \
} while (0)
#define AC(m, hs) do { acc[m].x = fmaf(hs, wvv.x, acc[m].x);                  \
                       acc[m].y = fmaf(hs, wvv.y, acc[m].y);                  \
                       acc[m].z = fmaf(hs, wvv.z, acc[m].z);                  \
                       acc[m].w = fmaf(hs, wvv.w, acc[m].w); } while (0)
#define COMPUTE(b, ph) do {                                                   \
    _Pragma("unroll")                                                         \
    for (int i_ = 0; i_ < 4; ++i_) {                                          \
        const int kk_ = (ph) * 4 + i_;                                        \
        const float4 wvv = *(const float4*)&wl[wv][b][i_ * 256 + ln * 4];     \
        const float4 h0 = ((const float4*)&hl[kk_][0])[0];                    \
        const float4 h1 = ((const float4*)&hl[kk_][0])[1];                    \
        const float4 h2 = ((const float4*)&hl[kk_][0])[2];                    \
        const float4 h3 = ((const float4*)&hl[kk_][0])[3];                    \
        AC(0,  h0.x); AC(1,  h0.y); AC(2,  h0.z); AC(3,  h0.w);               \
        AC(4,  h1.x); AC(5,  h1.y); AC(6,  h1.z); AC(7,  h1.w);               \
        AC(8,  h2.x); AC(9,  h2.y); AC(10, h2.z); AC(11, h2.w);               \
        AC(12, h3.x); AC(13, h3.y); AC(14, h3.z); AC(15, h3.w);               \
    }                                                                         \
} while (0)

    STAGE(0, 0);
    STAGE(1, 1);
    STAGE(2, 2);
    // steady state at iter ph: in flight = stages ph, ph+1, ph+2 = 12 loads.
    // WAITV8 -> stage(ph)'s 4 loads landed; ph+1/ph+2 still flying.
    // stage(ph+3) reuses buffer (ph+3)&3 == (ph-1)&3, consumed last iter
    // BY THIS WAVE (wave-private) — race-free without any barrier.
#pragma unroll 1
    for (int ph = 0; ph <= 13; ++ph) {
        WAITV8();
        if (ph <= 12) STAGE((ph + 3) & 3, ph + 3);
        COMPUTE(ph & 3, ph);
    }
    WAITV4();                          // stages 14,15 in flight -> 14 landed
    COMPUTE(14 & 3, 14);
    WAITV0();                          // 15 landed
    COMPUTE(15 & 3, 15);
#undef COMPUTE
#undef AC
#undef STAGE

    // partial-slice write: wave-coalesced 1 KB float4 stores per m row
    float* op = p2 + (size_t)blockIdx.y * (BN * NW2) + n0 + wv * 256 + ln * 4;
#pragma unroll
    for (int m = 0; m < BN; ++m)
        *(float4*)(op + (size_t)m * NW2) = acc[m];
}

// ===========================================================================
// K2r: xw[m][n] = b2[n] + sum_{ks<KSL} p2[ks][m][n]  (float4, coalesced)
// FUSED k3: for the x_a half (n < 16384), also accumulate
// t[m][r] += sum_c x[m][c] * xw[m][c*8+r] via block-local float4 reduce +
// 8 atomics/block (t zeroed by the h_pre memset; 2K atomics total).
__global__ void k2r(const float* __restrict__ p2, const float* __restrict__ b2,
                    const float* __restrict__ x, float* __restrict__ xw,
                    float* __restrict__ t) {
    const int tid = threadIdx.x;
    const int i   = blockIdx.x * 256 + tid;     // float4 idx over 131072
    const int m   = i >> 13;                    // 8192 float4 per m
    const int f4  = i & 8191;
    float4 s = ((const float4*)b2)[f4];
    const float4* p = (const float4*)p2 + i;
#pragma unroll
    for (int ks = 0; ks < KSL; ++ks) {
        float4 v = p[(size_t)ks * (BN * NW2 / 4)];
        s.x += v.x; s.y += v.y; s.z += v.z; s.w += v.w;
    }
    ((float4*)xw)[i] = s;

    // fused t-reduction (block-uniform predicate: first 16 of 32 blocks per m)
    const bool is_xa = (f4 < 4096);             // n = f4*4 < 16384
    if (is_xa) {
        __shared__ float4 lr[256];
        const int c = f4 >> 1;                  // n=c*8+r0, r0=(tid&1)*4
        const float xv = x[m * DN + c];
        lr[tid] = make_float4(s.x * xv, s.y * xv, s.z * xv, s.w * xv);
        // parity-preserving tree (strides even): lr[0]=sum even, lr[1]=sum odd
        for (int off = 128; off >= 2; off >>= 1) {
            __syncthreads();
            if (tid < off) {
                float4 a = lr[tid], b = lr[tid + off];
                lr[tid] = make_float4(a.x + b.x, a.y + b.y, a.z + b.z, a.w + b.w);
            }
        }
        if (tid == 0) {
            atomicAdd(&t[m * 8 + 0], lr[0].x); atomicAdd(&t[m * 8 + 1], lr[0].y);
            atomicAdd(&t[m * 8 + 2], lr[0].z); atomicAdd(&t[m * 8 + 3], lr[0].w);
        } else if (tid == 1) {
            atomicAdd(&t[m * 8 + 4], lr[1].x); atomicAdd(&t[m * 8 + 5], lr[1].y);
            atomicAdd(&t[m * 8 + 6], lr[1].z); atomicAdd(&t[m * 8 + 7], lr[1].w);
        }
    }
}

// ===========================================================================
// K4m: p4[cs][m][o] = sum_{c in 32-chunk} x[m][c] * base[c][o]
// grid (2, 64, 2), block 256. Thread owns float4 of o for 8 m; no LDS.
#define K4ACC(i, xv) do { acc[i].x = fmaf((xv), b.x, acc[i].x); \
                          acc[i].y = fmaf((xv), b.y, acc[i].y); \
                          acc[i].z = fmaf((xv), b.z, acc[i].z); \
                          acc[i].w = fmaf((xv), b.w, acc[i].w); } while (0)
__global__ __launch_bounds__(256) void k4m(const float* __restrict__ x,
                                           const float* __restrict__ base,
                                           float* __restrict__ p4) {
    const int o4 = blockIdx.x * 256 + threadIdx.x;   // [0, 512)
    const int c0 = blockIdx.y * 32;
    const int m0 = blockIdx.z * 8;
    float4 acc[8];
#pragma unroll
    for (int m = 0; m < 8; ++m) acc[m] = make_float4(0.f, 0.f, 0.f, 0.f);

    const float4* bp = (const float4*)base + (size_t)c0 * (DN / 4) + o4;
    float4 bbuf[8];
#pragma unroll
    for (int u = 0; u < 8; ++u) bbuf[u] = bp[(size_t)u * (DN / 4)];

    for (int cb = 0; cb < 32; cb += 8) {
#pragma unroll
        for (int u = 0; u < 8; ++u) {
            const int cc = cb + u;
            const float4 b = bbuf[u];
            const int cn = (cc + 8 < 32) ? (cc + 8) : cc;    // uniform clamp
            bbuf[u] = bp[(size_t)cn * (DN / 4)];
            const float x0 = x[(m0 + 0) * DN + c0 + cc];
            const float x1 = x[(m0 + 1) * DN + c0 + cc];
            const float x2 = x[(m0 + 2) * DN + c0 + cc];
            const float x3 = x[(m0 + 3) * DN + c0 + cc];
            const float x4 = x[(m0 + 4) * DN + c0 + cc];
            const float x5 = x[(m0 + 5) * DN + c0 + cc];
            const float x6 = x[(m0 + 6) * DN + c0 + cc];
            const float x7 = x[(m0 + 7) * DN + c0 + cc];
            K4ACC(0, x0); K4ACC(1, x1); K4ACC(2, x2); K4ACC(3, x3);
            K4ACC(4, x4); K4ACC(5, x5); K4ACC(6, x6); K4ACC(7, x7);
        }
    }
    float4* op = (float4*)p4 + (size_t)blockIdx.y * (BN * DN / 4)
               + (size_t)m0 * (DN / 4) + o4;
#pragma unroll
    for (int m = 0; m < 8; ++m) op[(size_t)m * (DN / 4)] = acc[m];
}

// ===========================================================================
// K5: out[m][o] = x[m][o] + sum_{cs<64} p4[cs][m][o] + sum_r t[m][r]*x_b[m][o][r]
__global__ void k5(const float* __restrict__ x, const float* __restrict__ p4,
                   const float* __restrict__ xw, const float* __restrict__ t,
                   float* __restrict__ out) {
    const int i = blockIdx.x * 256 + threadIdx.x;   // [0, 32768)
    const int m = i >> 11, o = i & (DN - 1);
    float s = x[i];
    const float* p = p4 + i;
#pragma unroll 8
    for (int ks = 0; ks < 64; ++ks) s += p[ks * (BN * DN)];
    const float4 xb0 = *(const float4*)(xw + (size_t)m * NW2 + HALFN + o * 8);
    const float4 xb1 = *(const float4*)(xw + (size_t)m * NW2 + HALFN + o * 8 + 4);
    const float* tm = t + m * 8;
    s += tm[0] * xb0.x + tm[1] * xb0.y + tm[2] * xb0.z + tm[3] * xb0.w
       + tm[4] * xb1.x + tm[5] * xb1.y + tm[6] * xb1.z + tm[7] * xb1.w;
    out[i] = s;
}

// ===========================================================================
extern "C" void kernel_launch(void* const* d_in, const int* in_sizes, int n_in,
                              void* d_out, int out_size, void* d_ws, size_t ws_size,
                              hipStream_t stream) {
    const float* x    = (const float*)d_in[0];
    const float* ada  = (const float*)d_in[1];
    const float* base = (const float*)d_in[2];
    const float* w1   = (const float*)d_in[3];
    const float* b1   = (const float*)d_in[4];
    const float* w2   = (const float*)d_in[5];
    const float* b2   = (const float*)d_in[6];
    float* out = (float*)d_out;
    char* ws = (char*)d_ws;

    // ws layout (bytes):
    //   p2    @ 0           (16 * 16*32768*4 = 33,554,432)
    //   xw    @ 33,554,432  (2,097,152)
    //   p4    @ 35,651,584  (64 * 16*2048*4 = 8,388,608)
    //   h_pre @ 44,040,192  (65,536)   \ one memset covers both
    //   t     @ 44,105,728  (512)      /
    //   h_t   @ 44,106,240  (65,536)
    float* p2    = (float*)(ws);
    float* xw    = (float*)(ws + 33554432);
    float* p4    = (float*)(ws + 35651584);
    float* h_pre = (float*)(ws + 44040192);
    float* t     = (float*)(ws + 44105728);
    float* h_t   = (float*)(ws + 44106240);

    hipMemsetAsync(h_pre, 0, 66048, stream);   // h_pre + t atomic accumulators

    k1a <<<dim3(4, 32),    256, 0, stream>>>(ada, w1, h_pre);
    k1bt<<<64,             256, 0, stream>>>(h_pre, b1, h_t);
    k2w <<<dim3(32, KSL),  256, 0, stream>>>(h_t, w2, p2);
    k4m <<<dim3(2, 64, 2), 256, 0, stream>>>(x, base, p4);
    k2r <<<512,            256, 0, stream>>>(p2, b2, x, xw, t);
    k5  <<<128,            256, 0, stream>>>(x, p4, xw, t, out);
}